// Round 8
// baseline (161.619 us; speedup 1.0000x reference)
//
#include <hip/hip_runtime.h>
#include <math.h>

#define NCOL 32
#define DDIM 512
#define NPAIR 16
#define CATS 10
#define ROW_STRIDE (NCOL * DDIM)   /* 16384 floats between consecutive b rows */

#define NUM_ROWS 16                /* rows per num wave  */
#define CAT_ROWS 32                /* rows per cat wave  */

// v += dpp_permuted(v). old=0 / bound_ctrl=false: masked-off rows contribute 0.
template <int CTRL, int ROW_MASK>
__device__ __forceinline__ float dpp_add(float v) {
    int t = __builtin_amdgcn_update_dpp(0, __float_as_int(v), CTRL, ROW_MASK, 0xf, false);
    return v + __int_as_float(t);
}
// pure DPP move: returns permuted value (0 in masked-off rows).
template <int CTRL, int ROW_MASK>
__device__ __forceinline__ float dpp_mov(float v) {
    int t = __builtin_amdgcn_update_dpp(0, __float_as_int(v), CTRL, ROW_MASK, 0xf, false);
    return __int_as_float(t);
}

// After this: lane31 = sum(lanes 0..31), lane63 = sum(lanes 32..63). VALU only.
__device__ __forceinline__ float wave_reduce_halves(float v) {
    v = dpp_add<0x111, 0xf>(v);  // row_shr:1
    v = dpp_add<0x112, 0xf>(v);  // row_shr:2
    v = dpp_add<0x114, 0xf>(v);  // row_shr:4
    v = dpp_add<0x118, 0xf>(v);  // row_shr:8  -> lane15 of each row16 = row sum
    v = dpp_add<0x142, 0xa>(v);  // row_bcast:15 -> lane31, lane63 hold half-sums
    return v;
}
// Full 64-lane sum, valid in lane 63.
__device__ __forceinline__ float wave_reduce_full(float v) {
    v = wave_reduce_halves(v);
    v = dpp_add<0x143, 0xc>(v);  // row_bcast:31 into rows 2,3 -> lane63 = total
    return v;
}

// ======================= numeric kernel: 32 waves/CU =======================
#define NLOADROW(Ra, Rb, r) do {                                  \
    const float* _p = xb + (size_t)(r) * ROW_STRIDE;              \
    Ra = *(const float4*)(_p + lane * 4);                         \
    Rb = *(const float4*)(_p + 256 + lane * 4);                   \
} while (0)

#define NUM_ROW(Ra, Rb, idx) do {                                 \
    float s = Ra.x * w[0];                                        \
    s = fmaf(Ra.y, w[1], s);                                      \
    s = fmaf(Ra.z, w[2], s);                                      \
    s = fmaf(Ra.w, w[3], s);                                      \
    s = fmaf(Rb.x, w[4], s);                                      \
    s = fmaf(Rb.y, w[5], s);                                      \
    s = fmaf(Rb.z, w[6], s);                                      \
    s = fmaf(Rb.w, w[7], s);                                      \
    s = wave_reduce_full(s);                                      \
    if (lane == 63) ob[(size_t)(idx) * NCOL] = tanhf(s + bias);   \
} while (0)

__global__ __launch_bounds__(256, 8) void num_kernel(
    const float* __restrict__ x,
    const float* __restrict__ Wn,
    const float* __restrict__ bn,
    float* __restrict__ out)
{
    const int lane  = threadIdx.x & 63;
    const int wslot = threadIdx.x >> 6;
    const int wid   = __builtin_amdgcn_readfirstlane(blockIdx.x * 4 + wslot); // 0..8191
    const int p     = wid & (NPAIR - 1);
    const int chunk = wid >> 4;                       // 0..511
    const size_t b0 = (size_t)chunk * NUM_ROWS;

    float w[8];
    {
        float4 wa = *(const float4*)(Wn + p * DDIM + lane * 4);
        float4 wb = *(const float4*)(Wn + p * DDIM + 256 + lane * 4);
        w[0]=wa.x; w[1]=wa.y; w[2]=wa.z; w[3]=wa.w;
        w[4]=wb.x; w[5]=wb.y; w[6]=wb.z; w[7]=wb.w;
    }
    const float bias = __int_as_float(
        __builtin_amdgcn_readfirstlane(__float_as_int(bn[p])));
    const float* xb = x + b0 * ROW_STRIDE + (size_t)(2 * p) * DDIM;
    float* ob = out + b0 * NCOL + 2 * p;

    // depth-2 A/B prefetch (exactly the R2 numeric structure)
    float4 A0, A1, B0, B1;
    NLOADROW(A0, A1, 0);
    NLOADROW(B0, B1, 1);
    for (int i = 0; i < NUM_ROWS - 2; i += 2) {
        float4 C0, C1, D0, D1;
        NLOADROW(C0, C1, i + 2);
        NUM_ROW(A0, A1, i);
        NLOADROW(D0, D1, i + 3);
        NUM_ROW(B0, B1, i + 1);
        A0 = C0; A1 = C1; B0 = D0; B1 = D1;
    }
    NUM_ROW(A0, A1, NUM_ROWS - 2);
    NUM_ROW(B0, B1, NUM_ROWS - 1);
}

// ===================== categorical kernel: 16 waves/CU =====================
// counted vmcnt wait; "memory" clobber pins all memory ops (ds_read included)
#define WAITVM(n) asm volatile("s_waitcnt vmcnt(" #n ")" ::: "memory")

// stage one odd-col row (2 KiB) HBM -> wave-private LDS slot, zero VGPR cost
#define CISSUE(row, slot) do {                                                 \
    const float* _g = xb + (size_t)(row) * ROW_STRIDE;                         \
    float* _l = &slab[wslot][slot][0];                                         \
    _Pragma("unroll")                                                          \
    for (int _k = 0; _k < 2; ++_k)                                             \
        __builtin_amdgcn_global_load_lds(                                      \
            (const __attribute__((address_space(1))) unsigned int*)            \
                (_g + _k * 256 + lane * 4),                                    \
            (__attribute__((address_space(3))) unsigned int*)(_l + _k * 256),  \
            16, 0, 0);                                                         \
} while (0)

// consume one staged row: cat math byte-identical to all passing rounds
#define CPROC(slot, idx) do {                                                  \
    const float* pb = &slab[wslot][slot][0];                                   \
    float4 Oa = *(const float4*)(pb +   0 + 4 * lane);                         \
    float4 Ob = *(const float4*)(pb + 256 + 4 * lane);                         \
    double best = -1.0e300;                                                    \
    int bi = 0;                                                                \
    _Pragma("unroll")                                                          \
    for (int c = 0; c < CATS; ++c) {                                           \
        float s = Oa.x * wc[c];                                                \
        s = fmaf(Oa.y, wc[10 + c], s);                                         \
        s = fmaf(Oa.z, wc[20 + c], s);                                         \
        s = fmaf(Oa.w, wc[30 + c], s);                                         \
        s = fmaf(Ob.x, wc[40 + c], s);                                         \
        s = fmaf(Ob.y, wc[50 + c], s);                                         \
        s = fmaf(Ob.z, wc[60 + c], s);                                         \
        s = fmaf(Ob.w, wc[70 + c], s);                                         \
        s = wave_reduce_halves(s);                                             \
        float slo = dpp_mov<0x143, 0xc>(s);                                    \
        double d = (double)s + (double)slo + biasd[c];                         \
        if (d > best) { best = d; bi = c; }                                    \
    }                                                                          \
    if (lane == 63) ob[(size_t)(idx) * NCOL] = (float)bi;                      \
} while (0)

__global__ __launch_bounds__(256, 4) void cat_kernel(
    const float* __restrict__ x,
    const float* __restrict__ Wc,
    const float* __restrict__ bc,
    float* __restrict__ out)
{
    // wave-private 4-slot ring: 4 waves x 4 slots x 2 KiB = 32 KiB/block
    __shared__ float slab[4][4][512];

    const int lane  = threadIdx.x & 63;
    const int wslot = threadIdx.x >> 6;
    const int wid   = __builtin_amdgcn_readfirstlane(blockIdx.x * 4 + wslot); // 0..4095
    const int p     = wid & (NPAIR - 1);
    const int chunk = wid >> 4;            // 0..255
    const size_t b0 = (size_t)chunk * CAT_ROWS;

    float wc[80];  // wc[dd*10+c] low half (d=4*lane+dd), wc[40+dd*10+c] high half
    {
        const float* w0 = Wc + ((size_t)p * DDIM + lane * 4) * CATS;
        const float* w1 = Wc + ((size_t)p * DDIM + 256 + lane * 4) * CATS;
        #pragma unroll
        for (int k = 0; k < 10; ++k) {
            float4 t = *(const float4*)(w0 + k * 4);
            wc[4*k] = t.x; wc[4*k+1] = t.y; wc[4*k+2] = t.z; wc[4*k+3] = t.w;
        }
        #pragma unroll
        for (int k = 0; k < 10; ++k) {
            float4 t = *(const float4*)(w1 + k * 4);
            wc[40+4*k] = t.x; wc[40+4*k+1] = t.y; wc[40+4*k+2] = t.z; wc[40+4*k+3] = t.w;
        }
    }
    double biasd[CATS];  // wave-uniform -> SGPR pairs (as in all passing rounds)
    #pragma unroll
    for (int c = 0; c < CATS; ++c)
        biasd[c] = (double)__int_as_float(
            __builtin_amdgcn_readfirstlane(__float_as_int(bc[p * CATS + c])));

    const float* xb = x + b0 * ROW_STRIDE + (size_t)(2 * p + 1) * DDIM;
    float* ob = out + b0 * NCOL + 2 * p + 1;

    // ring pipeline, 3 rows ahead, vmcnt never drained to 0 in steady state.
    // Invariant at top of iter r: issued = L_0..L_{min(r+2,31)}; needing L_r
    // done leaves at most {L_{r+1}, L_{r+2}} = 4 ops outstanding -> vmcnt(4).
    CISSUE(0, 0);
    CISSUE(1, 1);
    CISSUE(2, 2);
    for (int r = 0; r < CAT_ROWS; ++r) {
        WAITVM(4);
        CPROC(r & 3, r);
        if (r + 3 < CAT_ROWS) CISSUE(r + 3, (r + 3) & 3);
    }
}

extern "C" void kernel_launch(void* const* d_in, const int* in_sizes, int n_in,
                              void* d_out, int out_size, void* d_ws, size_t ws_size,
                              hipStream_t stream) {
    const float* x  = (const float*)d_in[0];
    const float* Wn = (const float*)d_in[1];
    const float* bn = (const float*)d_in[2];
    const float* Wc = (const float*)d_in[3];
    const float* bc = (const float*)d_in[4];
    float* out = (float*)d_out;

    // num: 2048 blocks @ 8/CU resident (32 waves/CU), 16 rows/wave
    hipLaunchKernelGGL(num_kernel, dim3(2048), dim3(256), 0, stream,
                       x, Wn, bn, out);
    // cat: 1024 blocks @ 4/CU resident (16 waves/CU), 32 rows/wave
    hipLaunchKernelGGL(cat_kernel, dim3(1024), dim3(256), 0, stream,
                       x, Wc, bc, out);
}

// Round 9
// 160.268 us; speedup vs baseline: 1.0084x; 1.0084x over previous
//
#include <hip/hip_runtime.h>
#include <math.h>

#define NCOL 32
#define DDIM 512
#define NPAIR 16
#define CATS 10
#define ROWS 32                    /* rows per wave */
#define ROW_STRIDE (NCOL * DDIM)   /* 16384 floats between consecutive b rows */

// v += dpp_permuted(v). old=0 / bound_ctrl=false: masked-off rows contribute 0.
template <int CTRL, int ROW_MASK>
__device__ __forceinline__ float dpp_add(float v) {
    int t = __builtin_amdgcn_update_dpp(0, __float_as_int(v), CTRL, ROW_MASK, 0xf, false);
    return v + __int_as_float(t);
}
// pure DPP move: returns permuted value (0 in masked-off rows).
template <int CTRL, int ROW_MASK>
__device__ __forceinline__ float dpp_mov(float v) {
    int t = __builtin_amdgcn_update_dpp(0, __float_as_int(v), CTRL, ROW_MASK, 0xf, false);
    return __int_as_float(t);
}

// After this: lane31 = sum(lanes 0..31), lane63 = sum(lanes 32..63). VALU only.
__device__ __forceinline__ float wave_reduce_halves(float v) {
    v = dpp_add<0x111, 0xf>(v);  // row_shr:1
    v = dpp_add<0x112, 0xf>(v);  // row_shr:2
    v = dpp_add<0x114, 0xf>(v);  // row_shr:4
    v = dpp_add<0x118, 0xf>(v);  // row_shr:8  -> lane15 of each row16 = row sum
    v = dpp_add<0x142, 0xa>(v);  // row_bcast:15 -> lane31, lane63 hold half-sums
    return v;
}
// Full 64-lane sum, valid in lane 63.
__device__ __forceinline__ float wave_reduce_full(float v) {
    v = wave_reduce_halves(v);
    v = dpp_add<0x143, 0xc>(v);  // row_bcast:31 into rows 2,3 -> lane63 = total
    return v;
}

// counted vmcnt wait; "memory" clobber orders the following ds_reads
#define WAITVM(n) asm volatile("s_waitcnt vmcnt(" #n ")" ::: "memory")

// stage one pair-row (4 KiB: even col + odd col, contiguous) HBM -> LDS slot
#define ISSUE(row, slot) do {                                                  \
    const float* _g = xb + (size_t)(row) * ROW_STRIDE;                         \
    float* _l = &slab[wslot][slot][0];                                         \
    _Pragma("unroll")                                                          \
    for (int _k = 0; _k < 4; ++_k)                                             \
        __builtin_amdgcn_global_load_lds(                                      \
            (const __attribute__((address_space(1))) unsigned int*)            \
                (_g + _k * 256 + lane * 4),                                    \
            (__attribute__((address_space(3))) unsigned int*)(_l + _k * 256),  \
            16, 0, 0);                                                         \
} while (0)

// consume one staged row: math byte-identical to all passing rounds
#define PROC(slot, idx) do {                                                   \
    const float* pb = &slab[wslot][slot][0];                                   \
    float4 Ea = *(const float4*)(pb +   0 + 4 * lane);                         \
    float4 Eb = *(const float4*)(pb + 256 + 4 * lane);                         \
    float4 Oa = *(const float4*)(pb + 512 + 4 * lane);                         \
    float4 Ob = *(const float4*)(pb + 768 + 4 * lane);                         \
    double best = -1.0e300;                                                    \
    int bi = 0;                                                                \
    _Pragma("unroll")                                                          \
    for (int c = 0; c < CATS; ++c) {                                           \
        float s = Oa.x * wc[c];                                                \
        s = fmaf(Oa.y, wc[10 + c], s);                                         \
        s = fmaf(Oa.z, wc[20 + c], s);                                         \
        s = fmaf(Oa.w, wc[30 + c], s);                                         \
        s = fmaf(Ob.x, wc[40 + c], s);                                         \
        s = fmaf(Ob.y, wc[50 + c], s);                                         \
        s = fmaf(Ob.z, wc[60 + c], s);                                         \
        s = fmaf(Ob.w, wc[70 + c], s);                                         \
        s = wave_reduce_halves(s);                                             \
        float slo = dpp_mov<0x143, 0xc>(s);                                    \
        double d = (double)s + (double)slo + biasd[c];                         \
        if (d > best) { best = d; bi = c; }                                    \
    }                                                                          \
    float sn = Ea.x * w[0];                                                    \
    sn = fmaf(Ea.y, w[1], sn);                                                 \
    sn = fmaf(Ea.z, w[2], sn);                                                 \
    sn = fmaf(Ea.w, w[3], sn);                                                 \
    sn = fmaf(Eb.x, w[4], sn);                                                 \
    sn = fmaf(Eb.y, w[5], sn);                                                 \
    sn = fmaf(Eb.z, w[6], sn);                                                 \
    sn = fmaf(Eb.w, w[7], sn);                                                 \
    sn = wave_reduce_full(sn);                                                 \
    if (lane == 63) {                                                          \
        float2 o2 = make_float2(tanhf(sn + bias), (float)bi);                  \
        *(float2*)(ob + (size_t)(idx) * NCOL) = o2;                            \
    }                                                                          \
} while (0)

__global__ __launch_bounds__(256, 4) void pair_ring4_kernel(
    const float* __restrict__ x,
    const float* __restrict__ Wn,
    const float* __restrict__ bn,
    const float* __restrict__ Wc,
    const float* __restrict__ bc,
    float* __restrict__ out)
{
    // wave-private 2-slot ring: 4 waves x 2 slots x 4 KiB = 32 KiB/block
    // -> LDS allows 5 blocks/CU; VGPR cap (128 @ min-waves 4) gives 4/CU.
    __shared__ float slab[4][2][1024];

    const int lane  = threadIdx.x & 63;
    const int wslot = threadIdx.x >> 6;
    const int wid   = __builtin_amdgcn_readfirstlane(blockIdx.x * 4 + wslot); // 0..4095
    const int p     = wid & (NPAIR - 1);   // block's 4 waves = 4 consecutive pairs
    const int chunk = wid >> 4;            // 0..255
    const size_t b0 = (size_t)chunk * ROWS;

    // ---- numeric weights (per-lane slice of Wn[p])
    float w[8];
    {
        float4 wa = *(const float4*)(Wn + p * DDIM + lane * 4);
        float4 wb = *(const float4*)(Wn + p * DDIM + 256 + lane * 4);
        w[0]=wa.x; w[1]=wa.y; w[2]=wa.z; w[3]=wa.w;
        w[4]=wb.x; w[5]=wb.y; w[6]=wb.z; w[7]=wb.w;
    }
    const float bias = __int_as_float(
        __builtin_amdgcn_readfirstlane(__float_as_int(bn[p])));

    // ---- categorical weights: wc[dd*10+c] low half, wc[40+dd*10+c] high half
    float wc[80];
    {
        const float* w0 = Wc + ((size_t)p * DDIM + lane * 4) * CATS;
        const float* w1 = Wc + ((size_t)p * DDIM + 256 + lane * 4) * CATS;
        #pragma unroll
        for (int k = 0; k < 10; ++k) {
            float4 t = *(const float4*)(w0 + k * 4);
            wc[4*k] = t.x; wc[4*k+1] = t.y; wc[4*k+2] = t.z; wc[4*k+3] = t.w;
        }
        #pragma unroll
        for (int k = 0; k < 10; ++k) {
            float4 t = *(const float4*)(w1 + k * 4);
            wc[40+4*k] = t.x; wc[40+4*k+1] = t.y; wc[40+4*k+2] = t.z; wc[40+4*k+3] = t.w;
        }
    }
    double biasd[CATS];  // wave-uniform -> SGPR pairs, zero VGPR cost
    #pragma unroll
    for (int c = 0; c < CATS; ++c)
        biasd[c] = (double)__int_as_float(
            __builtin_amdgcn_readfirstlane(__float_as_int(bc[p * CATS + c])));

    // this wave's pair data: 1024 contiguous floats per row (even+odd cols)
    const float* xb = x + b0 * ROW_STRIDE + (size_t)(2 * p) * DDIM;
    float* ob = out + b0 * NCOL + 2 * p;

    // ---- 2-slot ring, vmcnt never drained to 0 in steady state.
    // top of iter r: outstanding = {L_r, L_{r+1}}; wait L_r -> vmcnt(4).
    // ISSUE(r+2) goes after PROC(r) (slot reuse), keeping depth 2.
    ISSUE(0, 0);
    ISSUE(1, 1);
    for (int r = 0; r < ROWS - 2; ++r) {
        WAITVM(4);
        PROC(r & 1, r);
        ISSUE(r + 2, r & 1);
    }
    WAITVM(4);
    PROC((ROWS - 2) & 1, ROWS - 2);
    WAITVM(0);
    PROC((ROWS - 1) & 1, ROWS - 1);
}

extern "C" void kernel_launch(void* const* d_in, const int* in_sizes, int n_in,
                              void* d_out, int out_size, void* d_ws, size_t ws_size,
                              hipStream_t stream) {
    const float* x  = (const float*)d_in[0];
    const float* Wn = (const float*)d_in[1];
    const float* bn = (const float*)d_in[2];
    const float* Wc = (const float*)d_in[3];
    const float* bc = (const float*)d_in[4];
    float* out = (float*)d_out;

    // 4096 waves: (pair 0..15) x (32-row chunk 0..255); 1024 blocks all
    // co-resident at 4 blocks/CU (16 waves/CU).
    hipLaunchKernelGGL(pair_ring4_kernel, dim3(1024), dim3(256), 0, stream,
                       x, Wn, bn, Wc, bc, out);
}

// Round 10
// 107.071 us; speedup vs baseline: 1.5095x; 1.4968x over previous
//
#include <hip/hip_runtime.h>
#include <math.h>

#define NCOL 32
#define DDIM 512
#define NPAIR 16
#define CATS 10
#define ROW_STRIDE (NCOL * DDIM)   /* 16384 floats between consecutive b rows */
#define NBODY 192                  /* row-stride between a block's rows       */
#define TOTROWS 8192

// v += dpp_permuted(v). old=0 / bound_ctrl=false: masked-off rows contribute 0.
template <int CTRL, int ROW_MASK>
__device__ __forceinline__ float dpp_add(float v) {
    int t = __builtin_amdgcn_update_dpp(0, __float_as_int(v), CTRL, ROW_MASK, 0xf, false);
    return v + __int_as_float(t);
}
// pure DPP move: returns permuted value (0 in masked-off rows).
template <int CTRL, int ROW_MASK>
__device__ __forceinline__ float dpp_mov(float v) {
    int t = __builtin_amdgcn_update_dpp(0, __float_as_int(v), CTRL, ROW_MASK, 0xf, false);
    return __int_as_float(t);
}

// After this: lane31 = sum(lanes 0..31), lane63 = sum(lanes 32..63). VALU only.
__device__ __forceinline__ float wave_reduce_halves(float v) {
    v = dpp_add<0x111, 0xf>(v);  // row_shr:1
    v = dpp_add<0x112, 0xf>(v);  // row_shr:2
    v = dpp_add<0x114, 0xf>(v);  // row_shr:4
    v = dpp_add<0x118, 0xf>(v);  // row_shr:8  -> lane15 of each row16 = row sum
    v = dpp_add<0x142, 0xa>(v);  // row_bcast:15 -> lane31, lane63 hold half-sums
    return v;
}
// Full 64-lane sum, valid in lane 63.
__device__ __forceinline__ float wave_reduce_full(float v) {
    v = wave_reduce_halves(v);
    v = dpp_add<0x143, 0xc>(v);  // row_bcast:31 into rows 2,3 -> lane63 = total
    return v;
}

// counted vmcnt wait; "memory" clobber orders the following ds_reads
#define WAITVM(n) asm volatile("s_waitcnt vmcnt(" #n ")" ::: "memory")

// stage one pair-row (4 KiB: even col + odd col, contiguous) HBM -> LDS slot
#define ISSUE(row, slot) do {                                                  \
    const float* _g = x + (size_t)(row) * ROW_STRIDE + xcoloff;                \
    float* _l = &slab[wslot][slot][0];                                         \
    _Pragma("unroll")                                                          \
    for (int _k = 0; _k < 4; ++_k)                                             \
        __builtin_amdgcn_global_load_lds(                                      \
            (const __attribute__((address_space(1))) unsigned int*)            \
                (_g + _k * 256 + lane * 4),                                    \
            (__attribute__((address_space(3))) unsigned int*)(_l + _k * 256),  \
            16, 0, 0);                                                         \
} while (0)

// consume one staged row: math byte-identical to all passing rounds
#define PROC(slot, row) do {                                                   \
    const float* pb = &slab[wslot][slot][0];                                   \
    float4 Ea = *(const float4*)(pb +   0 + 4 * lane);                         \
    float4 Eb = *(const float4*)(pb + 256 + 4 * lane);                         \
    float4 Oa = *(const float4*)(pb + 512 + 4 * lane);                         \
    float4 Ob = *(const float4*)(pb + 768 + 4 * lane);                         \
    double best = -1.0e300;                                                    \
    int bi = 0;                                                                \
    _Pragma("unroll")                                                          \
    for (int c = 0; c < CATS; ++c) {                                           \
        float s = Oa.x * wc[c];                                                \
        s = fmaf(Oa.y, wc[10 + c], s);                                         \
        s = fmaf(Oa.z, wc[20 + c], s);                                         \
        s = fmaf(Oa.w, wc[30 + c], s);                                         \
        s = fmaf(Ob.x, wc[40 + c], s);                                         \
        s = fmaf(Ob.y, wc[50 + c], s);                                         \
        s = fmaf(Ob.z, wc[60 + c], s);                                         \
        s = fmaf(Ob.w, wc[70 + c], s);                                         \
        s = wave_reduce_halves(s);                                             \
        float slo = dpp_mov<0x143, 0xc>(s);                                    \
        double d = (double)s + (double)slo + biasd[c];                         \
        if (d > best) { best = d; bi = c; }                                    \
    }                                                                          \
    float sn = Ea.x * w[0];                                                    \
    sn = fmaf(Ea.y, w[1], sn);                                                 \
    sn = fmaf(Ea.z, w[2], sn);                                                 \
    sn = fmaf(Ea.w, w[3], sn);                                                 \
    sn = fmaf(Eb.x, w[4], sn);                                                 \
    sn = fmaf(Eb.y, w[5], sn);                                                 \
    sn = fmaf(Eb.z, w[6], sn);                                                 \
    sn = fmaf(Eb.w, w[7], sn);                                                 \
    sn = wave_reduce_full(sn);                                                 \
    if (lane == 63) {                                                          \
        float2 o2 = make_float2(tanhf(sn + bias), (float)bi);                  \
        *(float2*)(out + (size_t)(row) * NCOL + 2 * p) = o2;                   \
    }                                                                          \
} while (0)

// Persistent kernel: grid = 768 blocks = exactly 3 blocks/CU resident, so
// there are NO dispatch rounds (the 1024-block variants paid ~2x round tax).
// Each wave owns pair p and grid-strides over rows body, body+192, ...
__global__ __launch_bounds__(256, 3) void pair_persist_kernel(
    const float* __restrict__ x,
    const float* __restrict__ Wn,
    const float* __restrict__ bn,
    const float* __restrict__ Wc,
    const float* __restrict__ bc,
    float* __restrict__ out)
{
    // wave-private 3-slot ring: 4 waves x 3 slots x 4 KiB = 48 KiB/block
    __shared__ float slab[4][3][1024];

    const int lane  = threadIdx.x & 63;
    const int wslot = threadIdx.x >> 6;
    const int q     = __builtin_amdgcn_readfirstlane(blockIdx.x & 3); // quad
    const int body  = __builtin_amdgcn_readfirstlane(blockIdx.x >> 2); // 0..191
    const int p     = __builtin_amdgcn_readfirstlane(q * 4 + wslot);   // pair
    const size_t xcoloff = (size_t)p * (2 * DDIM);  // float offset of pair cols

    // ---- numeric weights (per-lane slice of Wn[p])
    float w[8];
    {
        float4 wa = *(const float4*)(Wn + p * DDIM + lane * 4);
        float4 wb = *(const float4*)(Wn + p * DDIM + 256 + lane * 4);
        w[0]=wa.x; w[1]=wa.y; w[2]=wa.z; w[3]=wa.w;
        w[4]=wb.x; w[5]=wb.y; w[6]=wb.z; w[7]=wb.w;
    }
    const float bias = __int_as_float(
        __builtin_amdgcn_readfirstlane(__float_as_int(bn[p])));

    // ---- categorical weights: wc[dd*10+c] low half, wc[40+dd*10+c] high half
    float wc[80];
    {
        const float* w0 = Wc + ((size_t)p * DDIM + lane * 4) * CATS;
        const float* w1 = Wc + ((size_t)p * DDIM + 256 + lane * 4) * CATS;
        #pragma unroll
        for (int k = 0; k < 10; ++k) {
            float4 t = *(const float4*)(w0 + k * 4);
            wc[4*k] = t.x; wc[4*k+1] = t.y; wc[4*k+2] = t.z; wc[4*k+3] = t.w;
        }
        #pragma unroll
        for (int k = 0; k < 10; ++k) {
            float4 t = *(const float4*)(w1 + k * 4);
            wc[40+4*k] = t.x; wc[40+4*k+1] = t.y; wc[40+4*k+2] = t.z; wc[40+4*k+3] = t.w;
        }
    }
    double biasd[CATS];  // wave-uniform -> SGPR pairs
    #pragma unroll
    for (int c = 0; c < CATS; ++c)
        biasd[c] = (double)__int_as_float(
            __builtin_amdgcn_readfirstlane(__float_as_int(bc[p * CATS + c])));

    // rows: body + 192*j, j = 0..n-1  (n = 43 for body<128 else 42)
    const int n = (TOTROWS - body + NBODY - 1) / NBODY;

    // ---- depth-3 ring over grid-strided rows; vmcnt never drains mid-loop.
    // top of iter j: outstanding = rows j,j+1,j+2 (12 ops); vmcnt(8) -> row j.
    ISSUE(body,             0);
    ISSUE(body + NBODY,     1);
    ISSUE(body + 2 * NBODY, 2);

    int s = 0;
    int r = body;                       // row being processed
    int ri = body + 3 * NBODY;          // next row to issue
    for (int j = 0; j < n - 3; ++j) {
        WAITVM(8);
        PROC(s, r);
        ISSUE(ri, s);
        s = (s == 2) ? 0 : s + 1;
        r += NBODY;
        ri += NBODY;
    }
    WAITVM(8);
    PROC(s, r);
    s = (s == 2) ? 0 : s + 1;  r += NBODY;
    WAITVM(4);
    PROC(s, r);
    s = (s == 2) ? 0 : s + 1;  r += NBODY;
    WAITVM(0);
    PROC(s, r);
}

extern "C" void kernel_launch(void* const* d_in, const int* in_sizes, int n_in,
                              void* d_out, int out_size, void* d_ws, size_t ws_size,
                              hipStream_t stream) {
    const float* x  = (const float*)d_in[0];
    const float* Wn = (const float*)d_in[1];
    const float* bn = (const float*)d_in[2];
    const float* Wc = (const float*)d_in[3];
    const float* bc = (const float*)d_in[4];
    float* out = (float*)d_out;

    // 768 blocks = 4 quads x 192 bodies; exactly 3 blocks/CU co-resident.
    hipLaunchKernelGGL(pair_persist_kernel, dim3(768), dim3(256), 0, stream,
                       x, Wn, bn, Wc, bc, out);
}